// Round 11
// baseline (1181.014 us; speedup 1.0000x reference)
//
#include <hip/hip_runtime.h>
#include <hip/hip_bf16.h>
#include <math.h>

// Problem constants (B=8, H=W=256, K=11 taps, thresh 0.2)
#define HH 256
#define WW 256
#define HW (HH*WW)
#define BB 8

typedef __hip_bfloat16 bf16;
typedef __attribute__((ext_vector_type(8))) short short8;    // 8 bf16 (4 VGPRs)
typedef __attribute__((ext_vector_type(4))) float f32x4;     // 16x16 MFMA acc
typedef __attribute__((ext_vector_type(16))) float f32x16;   // 32x32 MFMA acc

#define AS1 __attribute__((address_space(1)))
#define AS3 __attribute__((address_space(3)))

// v11 = v10 (barrier-free wave-private staging) with the DMA-destination fix:
// global_load_lds's LDS pointer must be WAVE-UNIFORM (backend readfirstlane's
// the first ACTIVE lane; HW adds lane*16). v10 passed base + lane*16, which
// broke whenever lane 0 was exec-masked (image borders) -> whole-wave stage
// shifted 64B -> absmax 0.73. v11 passes the uniform base only.
// Everything else identical to v10: no __syncthreads in conv kernels; wave
// owns a private 3-row LDS region; per-wave s_waitcnt lgkmcnt(0) (WAR) /
// vmcnt(0) (RAW) + sched_barrier(0); 32x32x16 MFMA with verified layouts
// and the (px>>1)&3 swizzle.

// ---------------------------------------------------------------------------
// Weight reorder: OIHW f32 -> [t][co][ci] bf16 (t = ky*3+kx)
// ---------------------------------------------------------------------------
template<int CO, int CI>
__global__ __launch_bounds__(256) void reorder_w(const float* __restrict__ w,
                                                 bf16* __restrict__ wr)
{
    int idx = blockIdx.x * 256 + threadIdx.x;
    if (idx >= 9 * CO * CI) return;
    int ci = idx % CI;
    int co = (idx / CI) % CO;
    int t  = idx / (CI * CO);
    wr[idx] = __float2bfloat16(w[((size_t)co * CI + ci) * 9 + t]);
}

// Both head weights -> one [9][32][64] bf16 buffer: co 0..10 = wh, 16..26 = wv.
__global__ __launch_bounds__(256) void reorder_w_head2(const float* __restrict__ wh,
                                                       const float* __restrict__ wv,
                                                       bf16* __restrict__ wr)
{
    int idx = blockIdx.x * 256 + threadIdx.x;
    if (idx >= 9 * 32 * 64) return;
    int ci = idx % 64;
    int co = (idx / 64) % 32;
    int t  = idx / (64 * 32);
    const float* src = (co < 16) ? wh : wv;
    int c = co & 15;
    float v = (c < 11) ? src[((size_t)c * 64 + ci) * 9 + t] : 0.0f;
    wr[idx] = __float2bfloat16(v);
}

// ---------------------------------------------------------------------------
// Shared-slab helpers (used by the barriered head kernel only).
// ---------------------------------------------------------------------------
template<int ROWS, int TPB>
__device__ __forceinline__ void zero_oob(bf16* __restrict__ s0,
                                         bf16* __restrict__ s1,
                                         int tid, int x0, int y0)
{
    constexpr int UNITS = (ROWS + 2) * 264;      // 16B units per buffer
    const short8 z8 = {0,0,0,0,0,0,0,0};
    for (int e = tid; e < UNITS; e += TPB) {
        int row = e / 264, rem = e - row * 264;
        int px = rem >> 2;
        int yy = y0 - 1 + row, xx = x0 - 1 + px;
        if (yy < 0 || yy >= HH || xx < 0 || xx >= WW) {
            *(short8*)(s0 + (size_t)e * 8) = z8;
            *(short8*)(s1 + (size_t)e * 8) = z8;
        }
    }
}

template<int CIN, int ROWS, int TPB>
__device__ __forceinline__ void stage_async(const bf16* __restrict__ in_i,
                                            bf16* __restrict__ slab,
                                            int tid, int x0, int y0, int k0)
{
    constexpr int UNITS = (ROWS + 2) * 264;
    const int lane = tid & 63;
    const int wb   = tid - lane;                 // wave's base unit
    for (int base = wb; base < UNITS; base += TPB) {
        int e = base + lane;
        int row = e / 264, rem = e - row * 264;
        int px = rem >> 2, slot = rem & 3;
        int seg = slot ^ ((px >> 1) & 3);
        int yy = y0 - 1 + row, xx = x0 - 1 + px;
        bool ok = (e < UNITS) && (yy >= 0) && (yy < HH) && (xx >= 0) && (xx < WW);
        if (ok) {
            const bf16* g = in_i + ((size_t)(yy * WW + xx)) * CIN + k0 + seg * 8;
            __builtin_amdgcn_global_load_lds((const AS1 void*)g,
                                             (AS3 void*)(slab + (size_t)base * 8),
                                             16, 0, 0);
        }
    }
}

// ---------------------------------------------------------------------------
// conv1: 3x3 conv over concat(rgb,depth) [4ch f32 planar], ReLU,
// output NHWC bf16 [G][HW][64]. blockIdx.y = img*64 + ytile.
// ---------------------------------------------------------------------------
template<int COC>
__global__ __launch_bounds__(256) void conv3x3_first(const float* __restrict__ rgb,
                                                     const float* __restrict__ depth,
                                                     const float* __restrict__ w,
                                                     const float* __restrict__ bias,
                                                     bf16* __restrict__ out, int b0)
{
    const int tid = threadIdx.x;
    const int img = blockIdx.y >> 6;
    const int b   = b0 + img;
    const int x = blockIdx.x * 64 + (tid & 63);
    const int y = (blockIdx.y & 63) * 4 + (tid >> 6);
    const int cog = blockIdx.z * COC;

    const bool vy0 = (y > 0), vy2 = (y < HH - 1);
    const bool vx0 = (x > 0), vx2 = (x < WW - 1);
    bool val[9];
    int  off[9];
    {
        int t = 0;
        for (int dy = -1; dy <= 1; ++dy)
            for (int dx = -1; dx <= 1; ++dx) {
                val[t] = (dy < 0 ? vy0 : (dy > 0 ? vy2 : true)) &&
                         (dx < 0 ? vx0 : (dx > 0 ? vx2 : true));
                off[t] = dy * WW + dx;
                ++t;
            }
    }

    float acc[COC];
#pragma unroll
    for (int j = 0; j < COC; ++j) acc[j] = bias[cog + j];

    const int p0 = y * WW + x;
#pragma unroll
    for (int ci = 0; ci < 4; ++ci) {
        const float* p = (ci < 3) ? (rgb + ((size_t)(b * 3 + ci)) * HW + p0)
                                  : (depth + (size_t)b * HW + p0);
        float v[9];
#pragma unroll
        for (int t = 0; t < 9; ++t)
            v[t] = val[t] ? p[off[t]] : 0.0f;

        const float* wp = w + ((size_t)cog * 4 + ci) * 9;
#pragma unroll
        for (int j = 0; j < COC; ++j) {
            const float* wj = wp + (size_t)j * 4 * 9;
#pragma unroll
            for (int t = 0; t < 9; ++t)
                acc[j] = fmaf(wj[t], v[t], acc[j]);
        }
    }

    // vectorized bf16 store: COC=16 -> two short8 (32 B, 16B-aligned)
    bf16* op = out + (size_t)img * HW * 64 + (size_t)p0 * 64 + cog;
#pragma unroll
    for (int g = 0; g < COC / 8; ++g) {
        short8 s;
#pragma unroll
        for (int j = 0; j < 8; ++j) {
            bf16 h = __float2bfloat16(fmaxf(acc[g * 8 + j], 0.0f));
            s[j] = *reinterpret_cast<short*>(&h);
        }
        *(short8*)(op + g * 8) = s;
    }
}

// ---------------------------------------------------------------------------
// MFMA implicit-GEMM 3x3 conv v11: barrier-free wave-private staging.
// 4 waves = 4 rows. Wave wv owns LDS rows [wv-1..wv+1] (private region,
// halo duplicated). Per chunk: wave stages own 3 rows (global_load_lds with
// WAVE-UNIFORM LDS base; HW adds lane*16), waits OWN vmcnt(0), computes;
// lgkmcnt(0) before overwriting own buffer next chunk. No __syncthreads.
// Compute tiling per wave: 2 x-Mtiles x NT=COUT/32 Ntiles, 32x32x16 MFMA.
// in : NHWC bf16 [G][HW][CIN]   wr : bf16 [9][COUT][CIN]   out : [G][HW][COUT]
// ---------------------------------------------------------------------------
template<int CIN, int COUT, int WPB>
__global__ __launch_bounds__(256, WPB) void conv_mfma_v11(const bf16* __restrict__ in,
                                                          const bf16* __restrict__ wr,
                                                          const float* __restrict__ bias,
                                                          bf16* __restrict__ out)
{
    constexpr int NCH    = CIN / 32;
    constexpr int NT     = COUT / 32;         // N-tiles per wave (full COUT)
    constexpr int WROWE  = 3 * 66 * 32;       // elements per wave region
    constexpr int WUNITS = 3 * 264;           // 792 16B units per wave region
    __shared__ bf16 slab[4 * WROWE];          // 50,688 B

    const int tid  = threadIdx.x;
    const int lane = tid & 63;
    const int wv   = tid >> 6;                // wave = row within tile (0..3)
    const int ln31 = lane & 31;
    const int oct  = lane >> 5;               // k-octet selector
    const int img  = blockIdx.y >> 6;
    const int x0   = blockIdx.x * 64;
    const int y0   = (blockIdx.y & 63) * 4;
    const int yb   = y0 + wv - 1;             // global row of wave's LDS row 0

    const bf16* in_i  = in  + (size_t)img * HW * CIN;
    bf16*       out_i = out + (size_t)img * HW * COUT;
    bf16*       wslab = slab + (size_t)wv * WROWE;

    f32x16 acc[2][NT];
#pragma unroll
    for (int mt = 0; mt < 2; ++mt)
#pragma unroll
        for (int nt = 0; nt < NT; ++nt)
#pragma unroll
            for (int j = 0; j < 16; ++j) acc[mt][nt][j] = 0.0f;

    // Zero OOB units of this wave's region once (DMA never writes them,
    // single buffer reused across chunks -> they stay zero).
    {
        const short8 z8 = {0,0,0,0,0,0,0,0};
        for (int e = lane; e < WUNITS; e += 64) {
            int row = e / 264, rem = e - row * 264, px = rem >> 2;
            int yy = yb + row, xx = x0 - 1 + px;
            if (yy < 0 || yy >= HH || xx < 0 || xx >= WW)
                *(short8*)(wslab + (size_t)e * 8) = z8;
        }
    }

    for (int kc = 0; kc < NCH; ++kc) {
        const int k0 = kc * 32;

        // WAR: this wave's LDS ops (prologue zeros / prior ds_reads) must
        // retire before DMA overwrites the region.
        asm volatile("s_waitcnt lgkmcnt(0)" ::: "memory");
        __builtin_amdgcn_sched_barrier(0);

        // Stage own 3 rows for chunk kc. LDS base is WAVE-UNIFORM (`base`);
        // hardware adds lane*16. Global src is per-lane and carries the
        // swizzle. OOB lanes are exec-masked off (their units hold zeros).
        for (int base = 0; base < WUNITS; base += 64) {
            int e = base + lane;
            int row = e / 264, rem = e - row * 264;
            int px = rem >> 2, slot = rem & 3;
            int seg = slot ^ ((px >> 1) & 3);
            int yy = yb + row, xx = x0 - 1 + px;
            bool ok = (e < WUNITS) && (yy >= 0) && (yy < HH) && (xx >= 0) && (xx < WW);
            if (ok) {
                const bf16* g = in_i + ((size_t)(yy * WW + xx)) * CIN + k0 + seg * 8;
                __builtin_amdgcn_global_load_lds((const AS1 void*)g,
                                                 (AS3 void*)(wslab + (size_t)base * 8),
                                                 16, 0, 0);
            }
        }
        // RAW: wave's own DMA must land before its ds_reads.
        asm volatile("s_waitcnt vmcnt(0)" ::: "memory");
        __builtin_amdgcn_sched_barrier(0);

#pragma unroll
        for (int t = 0; t < 9; ++t) {
            const int dy = t / 3 - 1, dx = t % 3 - 1;
            const int lrow = dy + 1;                               // 0..2
#pragma unroll
            for (int ks = 0; ks < 2; ++ks) {
                short8 a[2];
#pragma unroll
                for (int mt = 0; mt < 2; ++mt) {
                    const int px   = mt * 32 + ln31 + dx + 1;      // 0..65
                    const int slot = (ks * 2 + oct) ^ ((px >> 1) & 3);
                    a[mt] = *(const short8*)(wslab + ((size_t)lrow * 66 + px) * 32 + slot * 8);
                }
#pragma unroll
                for (int nt = 0; nt < NT; ++nt) {
                    const int co = nt * 32 + ln31;
                    short8 bfr = *(const short8*)(wr + ((size_t)(t * COUT + co)) * CIN
                                                  + k0 + ks * 16 + oct * 8);
#pragma unroll
                    for (int mt = 0; mt < 2; ++mt)
                        acc[mt][nt] = __builtin_amdgcn_mfma_f32_32x32x16_bf16(
                                          a[mt], bfr, acc[mt][nt], 0, 0, 0);
                }
            }
        }
    }

    // Epilogue. 32x32 C/D: col(co) = lane&31, row(px) = (j&3)+8*(j>>2)+4*oct.
#pragma unroll
    for (int nt = 0; nt < NT; ++nt) {
        const int co = nt * 32 + ln31;
        const float bb = bias[co];
#pragma unroll
        for (int mt = 0; mt < 2; ++mt) {
            const int xb = x0 + mt * 32;
#pragma unroll
            for (int j = 0; j < 16; ++j) {
                const int m = (j & 3) + 8 * (j >> 2) + 4 * oct;
                const float v = fmaxf(acc[mt][nt][j] + bb, 0.0f);
                out_i[((size_t)(y0 + wv) * WW + (xb + m)) * COUT + co] = __float2bfloat16(v);
            }
        }
    }
}

// ---------------------------------------------------------------------------
// Merged heads (16x16 shapes, barriered shared slab — v9-proven): dbuf DMA
// staging, both kh and kv; per-pixel softmax via wave-private LDS transpose.
// ---------------------------------------------------------------------------
__global__ __launch_bounds__(256, 2) void head_mfma2(const bf16* __restrict__ in,
                                                     const bf16* __restrict__ wrp,
                                                     const float* __restrict__ bh,
                                                     const float* __restrict__ bv,
                                                     float* __restrict__ kh_base,
                                                     float* __restrict__ kv_base,
                                                     int b0)
{
    constexpr int SLABH = 6 * 66 * 32;
    __shared__ bf16  slab[2 * SLABH];       // 50,688 B
    __shared__ float smx[4][64][17];        // 17,408 B (wave-private slices)

    const int tid  = threadIdx.x;
    const int lane = tid & 63;
    const int wv   = tid >> 6;
    const int m    = lane & 15;
    const int q    = lane >> 4;
    const int img  = blockIdx.y >> 6;
    const int x0   = blockIdx.x * 64;
    const int y0   = (blockIdx.y & 63) * 4;
    const int y    = y0 + wv;

    const bf16* in_i = in + (size_t)img * HW * 64;

    f32x4 acc[4][2];
#pragma unroll
    for (int f = 0; f < 4; ++f) { acc[f][0] = (f32x4){0.f,0.f,0.f,0.f}; acc[f][1] = (f32x4){0.f,0.f,0.f,0.f}; }

    zero_oob<4, 256>(slab, slab + SLABH, tid, x0, y0);
    stage_async<64, 4, 256>(in_i, slab, tid, x0, y0, 0);

    int cur = 0;
    for (int kc = 0; kc < 2; ++kc) {
        __syncthreads();
        if (kc == 0)
            stage_async<64, 4, 256>(in_i, slab + SLABH, tid, x0, y0, 32);

        const bf16* sb = slab + (size_t)cur * SLABH;
        const int k0 = kc * 32;
#pragma unroll
        for (int t = 0; t < 9; ++t) {
            const int dy = t / 3 - 1, dx = t % 3 - 1;
            const int srow = wv + dy + 1;
            const bf16* wt = wrp + (size_t)t * 32 * 64 + (size_t)m * 64 + k0 + q * 8;
            short8 b0f = *(const short8*)(wt);
            short8 b1f = *(const short8*)(wt + 16 * 64);
#pragma unroll
            for (int f = 0; f < 4; ++f) {
                const int px = f * 16 + m + dx + 1;
                const int slot = q ^ ((px >> 1) & 3);
                short8 a = *(const short8*)(sb + (srow * 66 + px) * 32 + slot * 8);
                acc[f][0] = __builtin_amdgcn_mfma_f32_16x16x32_bf16(a, b0f, acc[f][0], 0, 0, 0);
                acc[f][1] = __builtin_amdgcn_mfma_f32_16x16x32_bf16(a, b1f, acc[f][1], 0, 0, 0);
            }
        }
        cur ^= 1;
    }

    // two heads sequentially; smx slice is wave-private (no barrier needed)
#pragma unroll
    for (int head = 0; head < 2; ++head) {
        const float* bias = head ? bv : bh;
        const float bb = (m < 11) ? bias[m] : 0.0f;
#pragma unroll
        for (int f = 0; f < 4; ++f)
#pragma unroll
            for (int r = 0; r < 4; ++r)
                smx[wv][f * 16 + q * 4 + r][m] = acc[f][head][r] + bb;

        float v[11];
#pragma unroll
        for (int j = 0; j < 11; ++j) v[j] = smx[wv][lane][j];
        float mx = v[0];
#pragma unroll
        for (int j = 1; j < 11; ++j) mx = fmaxf(mx, v[j]);
        float s = 0.0f;
#pragma unroll
        for (int j = 0; j < 11; ++j) { v[j] = expf(v[j] - mx); s += v[j]; }
        const float inv = 1.0f / s;

        float* op = (head ? kv_base : kh_base) + (size_t)(b0 + img) * 11 * HW
                    + (size_t)y * WW + x0 + lane;
#pragma unroll
        for (int j = 0; j < 11; ++j)
            op[(size_t)j * HW] = v[j] * inv;
    }
}

// ---------------------------------------------------------------------------
// Horizontal separable pass (full batch): h = sum_i kh_i * shift_x(rgb, i-5)
// ---------------------------------------------------------------------------
__global__ __launch_bounds__(256) void hpass(const float* __restrict__ rgb,
                                             const float* __restrict__ kh,
                                             float* __restrict__ h)
{
    int idx = blockIdx.x * 256 + threadIdx.x;     // b*HW + p, total 524288
    int b = idx >> 16;                            // HW = 2^16
    int p = idx & (HW - 1);
    int y = p >> 8;
    int x = p & 255;

    float kw[11];
#pragma unroll
    for (int i = 0; i < 11; ++i) kw[i] = kh[((size_t)(b * 11 + i)) * HW + p];

#pragma unroll
    for (int c = 0; c < 3; ++c) {
        const float* rp = rgb + ((size_t)(b * 3 + c)) * HW + (size_t)y * WW;
        float s = 0.0f;
#pragma unroll
        for (int i = 0; i < 11; ++i) {
            int xx = x + i - 5;
            if (xx >= 0 && xx < WW) s = fmaf(kw[i], rp[xx], s);
        }
        h[((size_t)(b * 3 + c)) * HW + p] = s;
    }
}

// ---------------------------------------------------------------------------
// Vertical pass + depth-mask composite. Writes final, blurred, mask.
// ---------------------------------------------------------------------------
__global__ __launch_bounds__(256) void vpass_compose(const float* __restrict__ h,
                                                     const float* __restrict__ kv,
                                                     const float* __restrict__ rgb,
                                                     const float* __restrict__ depth,
                                                     float* __restrict__ fin,
                                                     float* __restrict__ blur,
                                                     float* __restrict__ masko)
{
    int idx = blockIdx.x * 256 + threadIdx.x;
    int b = idx >> 16;                            // HW = 2^16
    int p = idx & (HW - 1);
    int y = p >> 8;
    int x = p & 255;

    float kw[11];
#pragma unroll
    for (int i = 0; i < 11; ++i) kw[i] = kv[((size_t)(b * 11 + i)) * HW + p];

    float d = depth[idx];
    float mk = (d > 0.2f) ? 1.0f : 0.0f;
    masko[idx] = mk;

#pragma unroll
    for (int c = 0; c < 3; ++c) {
        const float* hp = h + ((size_t)(b * 3 + c)) * HW + x;
        float s = 0.0f;
#pragma unroll
        for (int i = 0; i < 11; ++i) {
            int yy = y + i - 5;
            if (yy >= 0 && yy < HH) s = fmaf(kw[i], hp[(size_t)yy * WW], s);
        }
        size_t o = ((size_t)(b * 3 + c)) * HW + p;
        blur[o] = s;
        fin[o] = mk * rgb[o] + (1.0f - mk) * s;
    }
}

// ---------------------------------------------------------------------------
extern "C" void kernel_launch(void* const* d_in, const int* in_sizes, int n_in,
                              void* d_out, int out_size, void* d_ws, size_t ws_size,
                              hipStream_t stream)
{
    const float* rgb   = (const float*)d_in[0];
    const float* depth = (const float*)d_in[1];
    const float* w1 = (const float*)d_in[2];  const float* b1 = (const float*)d_in[3];
    const float* w2 = (const float*)d_in[4];  const float* b2 = (const float*)d_in[5];
    const float* w3 = (const float*)d_in[6];  const float* b3 = (const float*)d_in[7];
    const float* w4 = (const float*)d_in[8];  const float* b4 = (const float*)d_in[9];
    const float* w5 = (const float*)d_in[10]; const float* b5 = (const float*)d_in[11];
    const float* wh = (const float*)d_in[12]; const float* bh = (const float*)d_in[13];
    const float* wv = (const float*)d_in[14]; const float* bv = (const float*)d_in[15];

    float* out    = (float*)d_out;
    float* fin_o  = out;                    // [8,3,256,256]
    float* blur_o = out + 1572864;          // [8,3,256,256]
    float* kh_o   = out + 3145728;          // [8,11,256,256]
    float* kv_o   = out + 8912896;          // [8,11,256,256]
    float* mask_o = out + 14680064;         // [8,1,256,256]

    // --- Select batch group size G from ws_size (deterministic -> graph-safe).
    const size_t perG = (size_t)HW * 2 * (128 + 64 + 128);   // 41.9 MB per image
    const size_t wsz  = (size_t)1 * 1024 * 1024;
    int G = 1;
    if (ws_size >= 8 * perG + wsz) G = 8;
    else if (ws_size >= 4 * perG + wsz) G = 4;
    else if (ws_size >= 2 * perG + wsz) G = 2;

    char* ws = (char*)d_ws;
    const size_t szA = (size_t)G * HW * 128 * 2;
    const size_t szB = (size_t)G * HW * 64 * 2;
    const size_t szC = (size_t)G * HW * 128 * 2;
    bf16* bufA = (bf16*)ws;
    bf16* bufB = (bf16*)(ws + szA);
    bf16* bufC = (bf16*)(ws + szA + szB);
    float* hbuf = (float*)bufC;              // 6.3 MB <= szC

    bf16* w2r  = (bf16*)(ws + szA + szB + szC);
    bf16* w3r  = w2r + 9 * 64 * 64;
    bf16* w4r  = w3r + 9 * 128 * 64;
    bf16* w5r  = w4r + 9 * 128 * 128;
    bf16* whvr = w5r + 9 * 64 * 128;         // [9][32][64]

    dim3 blk(256);

    // one-time weight reorders (graph-safe: identical work every call)
    reorder_w<64, 64>  <<<dim3((9*64*64   + 255) / 256), blk, 0, stream>>>(w2, w2r);
    reorder_w<128, 64> <<<dim3((9*128*64  + 255) / 256), blk, 0, stream>>>(w3, w3r);
    reorder_w<128, 128><<<dim3((9*128*128 + 255) / 256), blk, 0, stream>>>(w4, w4r);
    reorder_w<64, 128> <<<dim3((9*64*128  + 255) / 256), blk, 0, stream>>>(w5, w5r);
    reorder_w_head2    <<<dim3((9*32*64   + 255) / 256), blk, 0, stream>>>(wh, wv, whvr);

    for (int b0 = 0; b0 < BB; b0 += G) {
        conv3x3_first<16><<<dim3(4, 64 * G, 4), blk, 0, stream>>>(rgb, depth, w1, b1, bufA, b0);
        // barrier-free conv layers: wave-private staging, 32x32x16 MFMA.
        conv_mfma_v11<64, 64, 3>  <<<dim3(4, 64 * G), blk, 0, stream>>>(bufA, w2r, b2, bufB);
        conv_mfma_v11<64, 128, 2> <<<dim3(4, 64 * G), blk, 0, stream>>>(bufB, w3r, b3, bufC);
        conv_mfma_v11<128, 128, 2><<<dim3(4, 64 * G), blk, 0, stream>>>(bufC, w4r, b4, bufA);
        conv_mfma_v11<128, 64, 3> <<<dim3(4, 64 * G), blk, 0, stream>>>(bufA, w5r, b5, bufB);
        head_mfma2<<<dim3(4, 64 * G), blk, 0, stream>>>(bufB, whvr, bh, bv, kh_o, kv_o, b0);
    }

    // separable blur + composite (full batch; bufC conv use dead by now)
    hpass<<<dim3(2048), blk, 0, stream>>>(rgb, kh_o, hbuf);
    vpass_compose<<<dim3(2048), blk, 0, stream>>>(hbuf, kv_o, rgb, depth,
                                                  fin_o, blur_o, mask_o);
}

// Round 12
// 767.949 us; speedup vs baseline: 1.5379x; 1.5379x over previous
//
#include <hip/hip_runtime.h>
#include <hip/hip_bf16.h>
#include <math.h>

// Problem constants (B=8, H=W=256, K=11 taps, thresh 0.2)
#define HH 256
#define WW 256
#define HW (HH*WW)
#define BB 8

typedef __hip_bfloat16 bf16;
typedef __attribute__((ext_vector_type(8))) short short8;    // 8 bf16 (4 VGPRs)
typedef __attribute__((ext_vector_type(4))) float f32x4;     // 16x16 MFMA acc
typedef __attribute__((ext_vector_type(16))) float f32x16;   // 32x32 MFMA acc

#define AS1 __attribute__((address_space(1)))
#define AS3 __attribute__((address_space(3)))

// v12 = v8 (best, 1017us: block-wide dbuf DMA staging, 1 barrier/chunk,
// mt4/nt2 32x32x16 tiling) + two verified/mechanistic fixes:
// 1. (px>>1)&3 slab swizzle (v9-verified: conflicts 9.4M -> 2.4M).
// 2. LANE-MAJOR weight layout [kc][t][ks][nt][lane][8]: the old [t][co][ci]
//    layout made every B-frag load a 64-cacheline scatter (per-lane stride =
//    CIN*2B) -> ~2300 L1 transactions per chunk per wave, exceeding the MFMA
//    work itself. This is the structure-invariant serializer that pinned all
//    variants at 160-170us/dispatch. Now each B-frag is ONE contiguous 1KB
//    coalesced load (16 lines, minimum) and consecutive (t,ks,nt) stream.

// ---------------------------------------------------------------------------
// Weight reorder: OIHW f32 -> lane-major [kc][t][ks][nt][lane][8] bf16.
// lane = oct*32 + ln31; frag element j: co = nt*32+ln31, ci = kc*32+ks*16+oct*8+j.
// ---------------------------------------------------------------------------
template<int CO, int CI>
__global__ __launch_bounds__(256) void reorder_w_cl(const float* __restrict__ w,
                                                    bf16* __restrict__ wr)
{
    int idx = blockIdx.x * 256 + threadIdx.x;
    if (idx >= 9 * CO * CI) return;
    int j    = idx & 7;
    int lane = (idx >> 3) & 63;
    int nt   = (idx >> 9) % (CO / 32);
    int rest = idx / (512 * (CO / 32));      // = (kc*9 + t)*2 + ks
    int ks   = rest & 1;
    int tt   = (rest >> 1) % 9;
    int kc   = rest / 18;
    int co = nt * 32 + (lane & 31);
    int ci = kc * 32 + ks * 16 + (lane >> 5) * 8 + j;
    wr[idx] = __float2bfloat16(w[((size_t)co * CI + ci) * 9 + tt]);
}

// Both head weights -> one [9][32][64] bf16 buffer: co 0..10 = wh, 16..26 = wv.
__global__ __launch_bounds__(256) void reorder_w_head2(const float* __restrict__ wh,
                                                       const float* __restrict__ wv,
                                                       bf16* __restrict__ wr)
{
    int idx = blockIdx.x * 256 + threadIdx.x;
    if (idx >= 9 * 32 * 64) return;
    int ci = idx % 64;
    int co = (idx / 64) % 32;
    int t  = idx / (64 * 32);
    const float* src = (co < 16) ? wh : wv;
    int c = co & 15;
    float v = (c < 11) ? src[((size_t)c * 64 + ci) * 9 + t] : 0.0f;
    wr[idx] = __float2bfloat16(v);
}

// ---------------------------------------------------------------------------
// One-time zero of the OOB halo slots of BOTH slab buffers (geometry-fixed,
// never touched by the DMA in any chunk). Whole-pixel zero: swizzle-agnostic.
// ---------------------------------------------------------------------------
template<int ROWS, int TPB>
__device__ __forceinline__ void zero_oob(bf16* __restrict__ s0,
                                         bf16* __restrict__ s1,
                                         int tid, int x0, int y0)
{
    constexpr int UNITS = (ROWS + 2) * 264;      // 16B units per buffer
    const short8 z8 = {0,0,0,0,0,0,0,0};
    for (int e = tid; e < UNITS; e += TPB) {
        int row = e / 264, rem = e - row * 264;
        int px = rem >> 2;
        int yy = y0 - 1 + row, xx = x0 - 1 + px;
        if (yy < 0 || yy >= HH || xx < 0 || xx >= WW) {
            *(short8*)(s0 + (size_t)e * 8) = z8;
            *(short8*)(s1 + (size_t)e * 8) = z8;
        }
    }
}

// ---------------------------------------------------------------------------
// Async DMA staging of one 32-ch chunk: global_load_lds, 16 B/lane.
// LDS dest = wave-uniform base (HW adds lane*16); global src carries the
// swizzle: slot s of pixel px holds channel-octet seg = s ^ ((px>>1)&3).
// ---------------------------------------------------------------------------
template<int CIN, int ROWS, int TPB>
__device__ __forceinline__ void stage_async(const bf16* __restrict__ in_i,
                                            bf16* __restrict__ slab,
                                            int tid, int x0, int y0, int k0)
{
    constexpr int UNITS = (ROWS + 2) * 264;
    const int lane = tid & 63;
    const int wb   = tid - lane;                 // wave's base unit
    for (int base = wb; base < UNITS; base += TPB) {
        int e = base + lane;
        int row = e / 264, rem = e - row * 264;
        int px = rem >> 2, slot = rem & 3;
        int seg = slot ^ ((px >> 1) & 3);
        int yy = y0 - 1 + row, xx = x0 - 1 + px;
        bool ok = (e < UNITS) && (yy >= 0) && (yy < HH) && (xx >= 0) && (xx < WW);
        if (ok) {
            const bf16* g = in_i + ((size_t)(yy * WW + xx)) * CIN + k0 + seg * 8;
            __builtin_amdgcn_global_load_lds((const AS1 void*)g,
                                             (AS3 void*)(slab + (size_t)base * 8),
                                             16, 0, 0);
        }
    }
}

// ---------------------------------------------------------------------------
// conv1: 3x3 conv over concat(rgb,depth) [4ch f32 planar], ReLU,
// output NHWC bf16 [G][HW][64]. blockIdx.y = img*64 + ytile.
// ---------------------------------------------------------------------------
template<int COC>
__global__ __launch_bounds__(256) void conv3x3_first(const float* __restrict__ rgb,
                                                     const float* __restrict__ depth,
                                                     const float* __restrict__ w,
                                                     const float* __restrict__ bias,
                                                     bf16* __restrict__ out, int b0)
{
    const int tid = threadIdx.x;
    const int img = blockIdx.y >> 6;
    const int b   = b0 + img;
    const int x = blockIdx.x * 64 + (tid & 63);
    const int y = (blockIdx.y & 63) * 4 + (tid >> 6);
    const int cog = blockIdx.z * COC;

    const bool vy0 = (y > 0), vy2 = (y < HH - 1);
    const bool vx0 = (x > 0), vx2 = (x < WW - 1);
    bool val[9];
    int  off[9];
    {
        int t = 0;
        for (int dy = -1; dy <= 1; ++dy)
            for (int dx = -1; dx <= 1; ++dx) {
                val[t] = (dy < 0 ? vy0 : (dy > 0 ? vy2 : true)) &&
                         (dx < 0 ? vx0 : (dx > 0 ? vx2 : true));
                off[t] = dy * WW + dx;
                ++t;
            }
    }

    float acc[COC];
#pragma unroll
    for (int j = 0; j < COC; ++j) acc[j] = bias[cog + j];

    const int p0 = y * WW + x;
#pragma unroll
    for (int ci = 0; ci < 4; ++ci) {
        const float* p = (ci < 3) ? (rgb + ((size_t)(b * 3 + ci)) * HW + p0)
                                  : (depth + (size_t)b * HW + p0);
        float v[9];
#pragma unroll
        for (int t = 0; t < 9; ++t)
            v[t] = val[t] ? p[off[t]] : 0.0f;

        const float* wp = w + ((size_t)cog * 4 + ci) * 9;
#pragma unroll
        for (int j = 0; j < COC; ++j) {
            const float* wj = wp + (size_t)j * 4 * 9;
#pragma unroll
            for (int t = 0; t < 9; ++t)
                acc[j] = fmaf(wj[t], v[t], acc[j]);
        }
    }

    // vectorized bf16 store: COC=16 -> two short8 (32 B, 16B-aligned)
    bf16* op = out + (size_t)img * HW * 64 + (size_t)p0 * 64 + cog;
#pragma unroll
    for (int g = 0; g < COC / 8; ++g) {
        short8 s;
#pragma unroll
        for (int j = 0; j < 8; ++j) {
            bf16 h = __float2bfloat16(fmaxf(acc[g * 8 + j], 0.0f));
            s[j] = *reinterpret_cast<short*>(&h);
        }
        *(short8*)(op + g * 8) = s;
    }
}

// ---------------------------------------------------------------------------
// MFMA implicit-GEMM 3x3 conv v12: v8 structure (dbuf staging, 1 barrier per
// chunk, 4 waves = 2 row-pairs x 2 co-halves, 4 Mtiles x NTT Ntiles per wave,
// 32x32x16) + (px>>1)&3 swizzle + lane-major coalesced B-weights.
// in : NHWC bf16 [G][HW][CIN]   wrb: lane-major (see reorder_w_cl)
// out: NHWC bf16 [G][HW][COUT]
// ---------------------------------------------------------------------------
template<int CIN, int COUT, int WPB>
__global__ __launch_bounds__(256, WPB) void conv_mfma_v12(const bf16* __restrict__ in,
                                                          const bf16* __restrict__ wrb,
                                                          const float* __restrict__ bias,
                                                          bf16* __restrict__ out)
{
    constexpr int NCH  = CIN / 32;
    constexpr int NTT  = COUT / 64;          // 32-co tiles per wave (co-half)
    constexpr int NTOT = COUT / 32;          // total 32-co tiles
    constexpr int SLAB = 6 * 66 * 32;        // elements per buffer (ROWS=4)
    __shared__ bf16 slab[2 * SLAB];

    const int tid  = threadIdx.x;
    const int lane = tid & 63;
    const int wv   = tid >> 6;               // 0..3
    const int ng   = wv & 1;                 // co-half
    const int rg   = wv >> 1;                // row pair (rows 2rg, 2rg+1)
    const int ln31 = lane & 31;
    const int oct  = lane >> 5;              // k-octet selector
    const int img  = blockIdx.y >> 6;
    const int x0   = blockIdx.x * 64;
    const int y0   = (blockIdx.y & 63) * 4;

    const bf16* in_i  = in  + (size_t)img * HW * CIN;
    bf16*       out_i = out + (size_t)img * HW * COUT;

    f32x16 acc[4][NTT];
#pragma unroll
    for (int mt = 0; mt < 4; ++mt)
#pragma unroll
        for (int nt = 0; nt < NTT; ++nt)
#pragma unroll
            for (int j = 0; j < 16; ++j) acc[mt][nt][j] = 0.0f;

    // prologue: zero halo slots of both buffers; stage chunk 0 into buf 0
    zero_oob<4, 256>(slab, slab + SLAB, tid, x0, y0);
    stage_async<CIN, 4, 256>(in_i, slab, tid, x0, y0, 0);

    int cur = 0;
    for (int kc = 0; kc < NCH; ++kc) {
        __syncthreads();                     // drains DMA of chunk kc; WAR-protects buf[cur^1]
        if (kc + 1 < NCH)
            stage_async<CIN, 4, 256>(in_i, slab + (size_t)(cur ^ 1) * SLAB,
                                     tid, x0, y0, (kc + 1) * 32);

        const bf16* sb = slab + (size_t)cur * SLAB;
#pragma unroll
        for (int t = 0; t < 9; ++t) {
            const int dy = t / 3 - 1, dx = t % 3 - 1;
#pragma unroll
            for (int ks = 0; ks < 2; ++ks) {
                short8 a[4];
#pragma unroll
                for (int mt = 0; mt < 4; ++mt) {
                    const int srow = 2 * rg + (mt >> 1) + dy + 1;      // 0..5
                    const int px   = (mt & 1) * 32 + ln31 + dx + 1;    // 0..65
                    const int slot = (ks * 2 + oct) ^ ((px >> 1) & 3);
                    a[mt] = *(const short8*)(sb + (srow * 66 + px) * 32 + slot * 8);
                }
#pragma unroll
                for (int nt = 0; nt < NTT; ++nt) {
                    const int gnt = ng * NTT + nt;
                    // lane-major coalesced: one contiguous 1KB wave-load
                    short8 bfr = *(const short8*)(wrb
                        + ((size_t)((((kc * 9 + t) * 2 + ks) * NTOT + gnt) * 64 + lane)) * 8);
#pragma unroll
                    for (int mt = 0; mt < 4; ++mt)
                        acc[mt][nt] = __builtin_amdgcn_mfma_f32_32x32x16_bf16(
                                          a[mt], bfr, acc[mt][nt], 0, 0, 0);
                }
            }
        }
        cur ^= 1;
    }

    // Epilogue. 32x32 C/D: col(co) = lane&31, row(px) = (j&3)+8*(j>>2)+4*oct.
#pragma unroll
    for (int nt = 0; nt < NTT; ++nt) {
        const int co = (ng * NTT + nt) * 32 + ln31;
        const float bb = bias[co];
#pragma unroll
        for (int mt = 0; mt < 4; ++mt) {
            const int r  = 2 * rg + (mt >> 1);
            const int xb = x0 + (mt & 1) * 32;
#pragma unroll
            for (int j = 0; j < 16; ++j) {
                const int m = (j & 3) + 8 * (j >> 2) + 4 * oct;
                const float v = fmaxf(acc[mt][nt][j] + bb, 0.0f);
                out_i[((size_t)(y0 + r) * WW + (xb + m)) * COUT + co] = __float2bfloat16(v);
            }
        }
    }
}

// ---------------------------------------------------------------------------
// Merged heads (16x16 shapes, v11-proven): dbuf DMA staging, both kh and kv;
// per-pixel softmax over 11 channels via wave-private padded LDS transpose.
// ---------------------------------------------------------------------------
__global__ __launch_bounds__(256, 2) void head_mfma2(const bf16* __restrict__ in,
                                                     const bf16* __restrict__ wrp,
                                                     const float* __restrict__ bh,
                                                     const float* __restrict__ bv,
                                                     float* __restrict__ kh_base,
                                                     float* __restrict__ kv_base,
                                                     int b0)
{
    constexpr int SLABH = 6 * 66 * 32;
    __shared__ bf16  slab[2 * SLABH];       // 50,688 B
    __shared__ float smx[4][64][17];        // 17,408 B (wave-private slices)

    const int tid  = threadIdx.x;
    const int lane = tid & 63;
    const int wv   = tid >> 6;
    const int m    = lane & 15;
    const int q    = lane >> 4;
    const int img  = blockIdx.y >> 6;
    const int x0   = blockIdx.x * 64;
    const int y0   = (blockIdx.y & 63) * 4;
    const int y    = y0 + wv;

    const bf16* in_i = in + (size_t)img * HW * 64;

    f32x4 acc[4][2];
#pragma unroll
    for (int f = 0; f < 4; ++f) { acc[f][0] = (f32x4){0.f,0.f,0.f,0.f}; acc[f][1] = (f32x4){0.f,0.f,0.f,0.f}; }

    zero_oob<4, 256>(slab, slab + SLABH, tid, x0, y0);
    stage_async<64, 4, 256>(in_i, slab, tid, x0, y0, 0);

    int cur = 0;
    for (int kc = 0; kc < 2; ++kc) {
        __syncthreads();
        if (kc == 0)
            stage_async<64, 4, 256>(in_i, slab + SLABH, tid, x0, y0, 32);

        const bf16* sb = slab + (size_t)cur * SLABH;
        const int k0 = kc * 32;
#pragma unroll
        for (int t = 0; t < 9; ++t) {
            const int dy = t / 3 - 1, dx = t % 3 - 1;
            const int srow = wv + dy + 1;
            const bf16* wt = wrp + (size_t)t * 32 * 64 + (size_t)m * 64 + k0 + q * 8;
            short8 b0f = *(const short8*)(wt);
            short8 b1f = *(const short8*)(wt + 16 * 64);
#pragma unroll
            for (int f = 0; f < 4; ++f) {
                const int px = f * 16 + m + dx + 1;
                const int slot = q ^ ((px >> 1) & 3);
                short8 a = *(const short8*)(sb + (srow * 66 + px) * 32 + slot * 8);
                acc[f][0] = __builtin_amdgcn_mfma_f32_16x16x32_bf16(a, b0f, acc[f][0], 0, 0, 0);
                acc[f][1] = __builtin_amdgcn_mfma_f32_16x16x32_bf16(a, b1f, acc[f][1], 0, 0, 0);
            }
        }
        cur ^= 1;
    }

    // two heads sequentially; smx slice is wave-private (no barrier needed)
#pragma unroll
    for (int head = 0; head < 2; ++head) {
        const float* bias = head ? bv : bh;
        const float bb = (m < 11) ? bias[m] : 0.0f;
#pragma unroll
        for (int f = 0; f < 4; ++f)
#pragma unroll
            for (int r = 0; r < 4; ++r)
                smx[wv][f * 16 + q * 4 + r][m] = acc[f][head][r] + bb;

        float v[11];
#pragma unroll
        for (int j = 0; j < 11; ++j) v[j] = smx[wv][lane][j];
        float mx = v[0];
#pragma unroll
        for (int j = 1; j < 11; ++j) mx = fmaxf(mx, v[j]);
        float s = 0.0f;
#pragma unroll
        for (int j = 0; j < 11; ++j) { v[j] = expf(v[j] - mx); s += v[j]; }
        const float inv = 1.0f / s;

        float* op = (head ? kv_base : kh_base) + (size_t)(b0 + img) * 11 * HW
                    + (size_t)y * WW + x0 + lane;
#pragma unroll
        for (int j = 0; j < 11; ++j)
            op[(size_t)j * HW] = v[j] * inv;
    }
}

// ---------------------------------------------------------------------------
// Horizontal separable pass (full batch): h = sum_i kh_i * shift_x(rgb, i-5)
// ---------------------------------------------------------------------------
__global__ __launch_bounds__(256) void hpass(const float* __restrict__ rgb,
                                             const float* __restrict__ kh,
                                             float* __restrict__ h)
{
    int idx = blockIdx.x * 256 + threadIdx.x;     // b*HW + p, total 524288
    int b = idx >> 16;                            // HW = 2^16
    int p = idx & (HW - 1);
    int y = p >> 8;
    int x = p & 255;

    float kw[11];
#pragma unroll
    for (int i = 0; i < 11; ++i) kw[i] = kh[((size_t)(b * 11 + i)) * HW + p];

#pragma unroll
    for (int c = 0; c < 3; ++c) {
        const float* rp = rgb + ((size_t)(b * 3 + c)) * HW + (size_t)y * WW;
        float s = 0.0f;
#pragma unroll
        for (int i = 0; i < 11; ++i) {
            int xx = x + i - 5;
            if (xx >= 0 && xx < WW) s = fmaf(kw[i], rp[xx], s);
        }
        h[((size_t)(b * 3 + c)) * HW + p] = s;
    }
}

// ---------------------------------------------------------------------------
// Vertical pass + depth-mask composite. Writes final, blurred, mask.
// ---------------------------------------------------------------------------
__global__ __launch_bounds__(256) void vpass_compose(const float* __restrict__ h,
                                                     const float* __restrict__ kv,
                                                     const float* __restrict__ rgb,
                                                     const float* __restrict__ depth,
                                                     float* __restrict__ fin,
                                                     float* __restrict__ blur,
                                                     float* __restrict__ masko)
{
    int idx = blockIdx.x * 256 + threadIdx.x;
    int b = idx >> 16;                            // HW = 2^16
    int p = idx & (HW - 1);
    int y = p >> 8;
    int x = p & 255;

    float kw[11];
#pragma unroll
    for (int i = 0; i < 11; ++i) kw[i] = kv[((size_t)(b * 11 + i)) * HW + p];

    float d = depth[idx];
    float mk = (d > 0.2f) ? 1.0f : 0.0f;
    masko[idx] = mk;

#pragma unroll
    for (int c = 0; c < 3; ++c) {
        const float* hp = h + ((size_t)(b * 3 + c)) * HW + x;
        float s = 0.0f;
#pragma unroll
        for (int i = 0; i < 11; ++i) {
            int yy = y + i - 5;
            if (yy >= 0 && yy < HH) s = fmaf(kw[i], hp[(size_t)yy * WW], s);
        }
        size_t o = ((size_t)(b * 3 + c)) * HW + p;
        blur[o] = s;
        fin[o] = mk * rgb[o] + (1.0f - mk) * s;
    }
}

// ---------------------------------------------------------------------------
extern "C" void kernel_launch(void* const* d_in, const int* in_sizes, int n_in,
                              void* d_out, int out_size, void* d_ws, size_t ws_size,
                              hipStream_t stream)
{
    const float* rgb   = (const float*)d_in[0];
    const float* depth = (const float*)d_in[1];
    const float* w1 = (const float*)d_in[2];  const float* b1 = (const float*)d_in[3];
    const float* w2 = (const float*)d_in[4];  const float* b2 = (const float*)d_in[5];
    const float* w3 = (const float*)d_in[6];  const float* b3 = (const float*)d_in[7];
    const float* w4 = (const float*)d_in[8];  const float* b4 = (const float*)d_in[9];
    const float* w5 = (const float*)d_in[10]; const float* b5 = (const float*)d_in[11];
    const float* wh = (const float*)d_in[12]; const float* bh = (const float*)d_in[13];
    const float* wv = (const float*)d_in[14]; const float* bv = (const float*)d_in[15];

    float* out    = (float*)d_out;
    float* fin_o  = out;                    // [8,3,256,256]
    float* blur_o = out + 1572864;          // [8,3,256,256]
    float* kh_o   = out + 3145728;          // [8,11,256,256]
    float* kv_o   = out + 8912896;          // [8,11,256,256]
    float* mask_o = out + 14680064;         // [8,1,256,256]

    // --- Select batch group size G from ws_size (deterministic -> graph-safe).
    const size_t perG = (size_t)HW * 2 * (128 + 64 + 128);   // 41.9 MB per image
    const size_t wsz  = (size_t)1 * 1024 * 1024;
    int G = 1;
    if (ws_size >= 8 * perG + wsz) G = 8;
    else if (ws_size >= 4 * perG + wsz) G = 4;
    else if (ws_size >= 2 * perG + wsz) G = 2;

    char* ws = (char*)d_ws;
    const size_t szA = (size_t)G * HW * 128 * 2;
    const size_t szB = (size_t)G * HW * 64 * 2;
    const size_t szC = (size_t)G * HW * 128 * 2;
    bf16* bufA = (bf16*)ws;
    bf16* bufB = (bf16*)(ws + szA);
    bf16* bufC = (bf16*)(ws + szA + szB);
    float* hbuf = (float*)bufC;              // 6.3 MB <= szC

    bf16* w2r  = (bf16*)(ws + szA + szB + szC);
    bf16* w3r  = w2r + 9 * 64 * 64;
    bf16* w4r  = w3r + 9 * 128 * 64;
    bf16* w5r  = w4r + 9 * 128 * 128;
    bf16* whvr = w5r + 9 * 64 * 128;         // [9][32][64]

    dim3 blk(256);

    // one-time weight reorders (graph-safe: identical work every call)
    reorder_w_cl<64, 64>  <<<dim3((9*64*64   + 255) / 256), blk, 0, stream>>>(w2, w2r);
    reorder_w_cl<128, 64> <<<dim3((9*128*64  + 255) / 256), blk, 0, stream>>>(w3, w3r);
    reorder_w_cl<128, 128><<<dim3((9*128*128 + 255) / 256), blk, 0, stream>>>(w4, w4r);
    reorder_w_cl<64, 128> <<<dim3((9*64*128  + 255) / 256), blk, 0, stream>>>(w5, w5r);
    reorder_w_head2       <<<dim3((9*32*64   + 255) / 256), blk, 0, stream>>>(wh, wv, whvr);

    for (int b0 = 0; b0 < BB; b0 += G) {
        conv3x3_first<16><<<dim3(4, 64 * G, 4), blk, 0, stream>>>(rgb, depth, w1, b1, bufA, b0);
        // conv layers: v8 structure + coalesced lane-major B-weights.
        conv_mfma_v12<64, 64, 3>  <<<dim3(4, 64 * G), blk, 0, stream>>>(bufA, w2r, b2, bufB);
        conv_mfma_v12<64, 128, 2> <<<dim3(4, 64 * G), blk, 0, stream>>>(bufB, w3r, b3, bufC);
        conv_mfma_v12<128, 128, 2><<<dim3(4, 64 * G), blk, 0, stream>>>(bufC, w4r, b4, bufA);
        conv_mfma_v12<128, 64, 3> <<<dim3(4, 64 * G), blk, 0, stream>>>(bufA, w5r, b5, bufB);
        head_mfma2<<<dim3(4, 64 * G), blk, 0, stream>>>(bufB, whvr, bh, bv, kh_o, kv_o, b0);
    }

    // separable blur + composite (full batch; bufC conv use dead by now)
    hpass<<<dim3(2048), blk, 0, stream>>>(rgb, kh_o, hbuf);
    vpass_compose<<<dim3(2048), blk, 0, stream>>>(hbuf, kv_o, rgb, depth,
                                                  fin_o, blur_o, mask_o);
}

// Round 14
// 747.749 us; speedup vs baseline: 1.5794x; 1.0270x over previous
//
#include <hip/hip_runtime.h>
#include <hip/hip_bf16.h>
#include <math.h>

// Problem constants (B=8, H=W=256, K=11 taps, thresh 0.2)
#define HH 256
#define WW 256
#define HW (HH*WW)
#define BB 8

typedef __hip_bfloat16 bf16;
typedef __attribute__((ext_vector_type(8))) short short8;    // 8 bf16 (4 VGPRs)
typedef __attribute__((ext_vector_type(4))) float f32x4;     // 16x16 MFMA acc
typedef __attribute__((ext_vector_type(16))) float f32x16;   // 32x32 MFMA acc

#define AS1 __attribute__((address_space(1)))
#define AS3 __attribute__((address_space(3)))

// v13 = v12 (best, 767.9us) + two LDS/L1-traffic fixes:
// 1. conv64 layers: dy-reuse — per (dx,ks) the 3 dy taps re-read rows
//    2rg+1/2rg+2 with IDENTICAL addresses (12 reads of 8 distinct frags).
//    Cache the 8 frags in registers, reuse across dy: A-reads -33%.
//    (conv128 keeps the v12 inner loop: its 252/256 reg budget can't take
//    the +16 VGPR without spilling; to revisit after freeing arch regs.)
// 2. head kernel: lane-major B weights ([kc][t][frag][lane][8]) — removes
//    the same 64-cacheline-per-load scatter that was just fixed for conv.

// ---------------------------------------------------------------------------
// Weight reorder: OIHW f32 -> lane-major [kc][t][ks][nt][lane][8] bf16.
// lane = oct*32 + ln31; frag element j: co = nt*32+ln31, ci = kc*32+ks*16+oct*8+j.
// ---------------------------------------------------------------------------
template<int CO, int CI>
__global__ __launch_bounds__(256) void reorder_w_cl(const float* __restrict__ w,
                                                    bf16* __restrict__ wr)
{
    int idx = blockIdx.x * 256 + threadIdx.x;
    if (idx >= 9 * CO * CI) return;
    int j    = idx & 7;
    int lane = (idx >> 3) & 63;
    int nt   = (idx >> 9) % (CO / 32);
    int rest = idx / (512 * (CO / 32));      // = (kc*9 + t)*2 + ks
    int ks   = rest & 1;
    int tt   = (rest >> 1) % 9;
    int kc   = rest / 18;
    int co = nt * 32 + (lane & 31);
    int ci = kc * 32 + ks * 16 + (lane >> 5) * 8 + j;
    wr[idx] = __float2bfloat16(w[((size_t)co * CI + ci) * 9 + tt]);
}

// Head weights -> lane-major [kc(2)][t(9)][fr(2)][lane(64)][8] bf16.
// fr selects co group (0: wh co 0..15-padded, 1: wv co 0..15-padded).
// element j of lane (m=lane&15, q=lane>>4): co = fr*16+m, ci = kc*32+q*8+j.
__global__ __launch_bounds__(256) void reorder_w_head2_lm(const float* __restrict__ wh,
                                                          const float* __restrict__ wv,
                                                          bf16* __restrict__ wr)
{
    int idx = blockIdx.x * 256 + threadIdx.x;
    if (idx >= 2 * 9 * 2 * 64 * 8) return;   // 18432
    int j    = idx & 7;
    int lane = (idx >> 3) & 63;
    int fr   = (idx >> 9) & 1;
    int t    = (idx >> 10) % 9;
    int kc   = (idx >> 10) / 9;
    int co   = fr * 16 + (lane & 15);
    int ci   = kc * 32 + (lane >> 4) * 8 + j;
    const float* src = (co < 16) ? wh : wv;
    int c = co & 15;
    float v = (c < 11) ? src[((size_t)c * 64 + ci) * 9 + t] : 0.0f;
    wr[idx] = __float2bfloat16(v);
}

// ---------------------------------------------------------------------------
// One-time zero of the OOB halo slots of BOTH slab buffers (geometry-fixed,
// never touched by the DMA in any chunk). Whole-pixel zero: swizzle-agnostic.
// ---------------------------------------------------------------------------
template<int ROWS, int TPB>
__device__ __forceinline__ void zero_oob(bf16* __restrict__ s0,
                                         bf16* __restrict__ s1,
                                         int tid, int x0, int y0)
{
    constexpr int UNITS = (ROWS + 2) * 264;      // 16B units per buffer
    const short8 z8 = {0,0,0,0,0,0,0,0};
    for (int e = tid; e < UNITS; e += TPB) {
        int row = e / 264, rem = e - row * 264;
        int px = rem >> 2;
        int yy = y0 - 1 + row, xx = x0 - 1 + px;
        if (yy < 0 || yy >= HH || xx < 0 || xx >= WW) {
            *(short8*)(s0 + (size_t)e * 8) = z8;
            *(short8*)(s1 + (size_t)e * 8) = z8;
        }
    }
}

// ---------------------------------------------------------------------------
// Async DMA staging of one 32-ch chunk: global_load_lds, 16 B/lane.
// LDS dest = wave-uniform base (HW adds lane*16); global src carries the
// swizzle: slot s of pixel px holds channel-octet seg = s ^ ((px>>1)&3).
// ---------------------------------------------------------------------------
template<int CIN, int ROWS, int TPB>
__device__ __forceinline__ void stage_async(const bf16* __restrict__ in_i,
                                            bf16* __restrict__ slab,
                                            int tid, int x0, int y0, int k0)
{
    constexpr int UNITS = (ROWS + 2) * 264;
    const int lane = tid & 63;
    const int wb   = tid - lane;                 // wave's base unit
    for (int base = wb; base < UNITS; base += TPB) {
        int e = base + lane;
        int row = e / 264, rem = e - row * 264;
        int px = rem >> 2, slot = rem & 3;
        int seg = slot ^ ((px >> 1) & 3);
        int yy = y0 - 1 + row, xx = x0 - 1 + px;
        bool ok = (e < UNITS) && (yy >= 0) && (yy < HH) && (xx >= 0) && (xx < WW);
        if (ok) {
            const bf16* g = in_i + ((size_t)(yy * WW + xx)) * CIN + k0 + seg * 8;
            __builtin_amdgcn_global_load_lds((const AS1 void*)g,
                                             (AS3 void*)(slab + (size_t)base * 8),
                                             16, 0, 0);
        }
    }
}

// ---------------------------------------------------------------------------
// conv1: 3x3 conv over concat(rgb,depth) [4ch f32 planar], ReLU,
// output NHWC bf16 [G][HW][64]. blockIdx.y = img*64 + ytile.
// ---------------------------------------------------------------------------
template<int COC>
__global__ __launch_bounds__(256) void conv3x3_first(const float* __restrict__ rgb,
                                                     const float* __restrict__ depth,
                                                     const float* __restrict__ w,
                                                     const float* __restrict__ bias,
                                                     bf16* __restrict__ out, int b0)
{
    const int tid = threadIdx.x;
    const int img = blockIdx.y >> 6;
    const int b   = b0 + img;
    const int x = blockIdx.x * 64 + (tid & 63);
    const int y = (blockIdx.y & 63) * 4 + (tid >> 6);
    const int cog = blockIdx.z * COC;

    const bool vy0 = (y > 0), vy2 = (y < HH - 1);
    const bool vx0 = (x > 0), vx2 = (x < WW - 1);
    bool val[9];
    int  off[9];
    {
        int t = 0;
        for (int dy = -1; dy <= 1; ++dy)
            for (int dx = -1; dx <= 1; ++dx) {
                val[t] = (dy < 0 ? vy0 : (dy > 0 ? vy2 : true)) &&
                         (dx < 0 ? vx0 : (dx > 0 ? vx2 : true));
                off[t] = dy * WW + dx;
                ++t;
            }
    }

    float acc[COC];
#pragma unroll
    for (int j = 0; j < COC; ++j) acc[j] = bias[cog + j];

    const int p0 = y * WW + x;
#pragma unroll
    for (int ci = 0; ci < 4; ++ci) {
        const float* p = (ci < 3) ? (rgb + ((size_t)(b * 3 + ci)) * HW + p0)
                                  : (depth + (size_t)b * HW + p0);
        float v[9];
#pragma unroll
        for (int t = 0; t < 9; ++t)
            v[t] = val[t] ? p[off[t]] : 0.0f;

        const float* wp = w + ((size_t)cog * 4 + ci) * 9;
#pragma unroll
        for (int j = 0; j < COC; ++j) {
            const float* wj = wp + (size_t)j * 4 * 9;
#pragma unroll
            for (int t = 0; t < 9; ++t)
                acc[j] = fmaf(wj[t], v[t], acc[j]);
        }
    }

    // vectorized bf16 store: COC=16 -> two short8 (32 B, 16B-aligned)
    bf16* op = out + (size_t)img * HW * 64 + (size_t)p0 * 64 + cog;
#pragma unroll
    for (int g = 0; g < COC / 8; ++g) {
        short8 s;
#pragma unroll
        for (int j = 0; j < 8; ++j) {
            bf16 h = __float2bfloat16(fmaxf(acc[g * 8 + j], 0.0f));
            s[j] = *reinterpret_cast<short*>(&h);
        }
        *(short8*)(op + g * 8) = s;
    }
}

// ---------------------------------------------------------------------------
// MFMA implicit-GEMM 3x3 conv v12 inner (for COUT=128 layers): dbuf staging,
// 1 barrier/chunk, 4 waves = 2 row-pairs x 2 co-halves, mt4 x NTT, 32x32x16,
// lane-major coalesced B.
// ---------------------------------------------------------------------------
template<int CIN, int COUT, int WPB>
__global__ __launch_bounds__(256, WPB) void conv_mfma_v12(const bf16* __restrict__ in,
                                                          const bf16* __restrict__ wrb,
                                                          const float* __restrict__ bias,
                                                          bf16* __restrict__ out)
{
    constexpr int NCH  = CIN / 32;
    constexpr int NTT  = COUT / 64;          // 32-co tiles per wave (co-half)
    constexpr int NTOT = COUT / 32;          // total 32-co tiles
    constexpr int SLAB = 6 * 66 * 32;        // elements per buffer (ROWS=4)
    __shared__ bf16 slab[2 * SLAB];

    const int tid  = threadIdx.x;
    const int lane = tid & 63;
    const int wv   = tid >> 6;               // 0..3
    const int ng   = wv & 1;                 // co-half
    const int rg   = wv >> 1;                // row pair (rows 2rg, 2rg+1)
    const int ln31 = lane & 31;
    const int oct  = lane >> 5;              // k-octet selector
    const int img  = blockIdx.y >> 6;
    const int x0   = blockIdx.x * 64;
    const int y0   = (blockIdx.y & 63) * 4;

    const bf16* in_i  = in  + (size_t)img * HW * CIN;
    bf16*       out_i = out + (size_t)img * HW * COUT;

    f32x16 acc[4][NTT];
#pragma unroll
    for (int mt = 0; mt < 4; ++mt)
#pragma unroll
        for (int nt = 0; nt < NTT; ++nt)
#pragma unroll
            for (int j = 0; j < 16; ++j) acc[mt][nt][j] = 0.0f;

    zero_oob<4, 256>(slab, slab + SLAB, tid, x0, y0);
    stage_async<CIN, 4, 256>(in_i, slab, tid, x0, y0, 0);

    int cur = 0;
    for (int kc = 0; kc < NCH; ++kc) {
        __syncthreads();                     // drains DMA of chunk kc; WAR-protects buf[cur^1]
        if (kc + 1 < NCH)
            stage_async<CIN, 4, 256>(in_i, slab + (size_t)(cur ^ 1) * SLAB,
                                     tid, x0, y0, (kc + 1) * 32);

        const bf16* sb = slab + (size_t)cur * SLAB;
#pragma unroll
        for (int t = 0; t < 9; ++t) {
            const int dy = t / 3 - 1, dx = t % 3 - 1;
#pragma unroll
            for (int ks = 0; ks < 2; ++ks) {
                short8 a[4];
#pragma unroll
                for (int mt = 0; mt < 4; ++mt) {
                    const int srow = 2 * rg + (mt >> 1) + dy + 1;      // 0..5
                    const int px   = (mt & 1) * 32 + ln31 + dx + 1;    // 0..65
                    const int slot = (ks * 2 + oct) ^ ((px >> 1) & 3);
                    a[mt] = *(const short8*)(sb + (srow * 66 + px) * 32 + slot * 8);
                }
#pragma unroll
                for (int nt = 0; nt < NTT; ++nt) {
                    const int gnt = ng * NTT + nt;
                    short8 bfr = *(const short8*)(wrb
                        + ((size_t)((((kc * 9 + t) * 2 + ks) * NTOT + gnt) * 64 + lane)) * 8);
#pragma unroll
                    for (int mt = 0; mt < 4; ++mt)
                        acc[mt][nt] = __builtin_amdgcn_mfma_f32_32x32x16_bf16(
                                          a[mt], bfr, acc[mt][nt], 0, 0, 0);
                }
            }
        }
        cur ^= 1;
    }

    // Epilogue. 32x32 C/D: col(co) = lane&31, row(px) = (j&3)+8*(j>>2)+4*oct.
#pragma unroll
    for (int nt = 0; nt < NTT; ++nt) {
        const int co = (ng * NTT + nt) * 32 + ln31;
        const float bb = bias[co];
#pragma unroll
        for (int mt = 0; mt < 4; ++mt) {
            const int r  = 2 * rg + (mt >> 1);
            const int xb = x0 + (mt & 1) * 32;
#pragma unroll
            for (int j = 0; j < 16; ++j) {
                const int m = (j & 3) + 8 * (j >> 2) + 4 * oct;
                const float v = fmaxf(acc[mt][nt][j] + bb, 0.0f);
                out_i[((size_t)(y0 + r) * WW + (xb + m)) * COUT + co] = __float2bfloat16(v);
            }
        }
    }
}

// ---------------------------------------------------------------------------
// conv v13 (for COUT=64 layers): same structure, dy-reuse A-fragment cache.
// Per (dx,ks): load the 8 distinct frags (4 srow x 2 mtx) ONCE, reuse across
// the 3 dy taps (v12 read 12 of these 8). A-reads per chunk: 72 -> 48.
// Registers: acc 64 + af 32 + ~84 arch <= 170 @ WPB=3.
// ---------------------------------------------------------------------------
template<int CIN, int COUT, int WPB>
__global__ __launch_bounds__(256, WPB) void conv_mfma_v13(const bf16* __restrict__ in,
                                                          const bf16* __restrict__ wrb,
                                                          const float* __restrict__ bias,
                                                          bf16* __restrict__ out)
{
    constexpr int NCH  = CIN / 32;
    constexpr int NTT  = COUT / 64;          // 1 for COUT=64
    constexpr int NTOT = COUT / 32;
    constexpr int SLAB = 6 * 66 * 32;
    __shared__ bf16 slab[2 * SLAB];

    const int tid  = threadIdx.x;
    const int lane = tid & 63;
    const int wv   = tid >> 6;
    const int ng   = wv & 1;
    const int rg   = wv >> 1;
    const int ln31 = lane & 31;
    const int oct  = lane >> 5;
    const int img  = blockIdx.y >> 6;
    const int x0   = blockIdx.x * 64;
    const int y0   = (blockIdx.y & 63) * 4;

    const bf16* in_i  = in  + (size_t)img * HW * CIN;
    bf16*       out_i = out + (size_t)img * HW * COUT;

    f32x16 acc[4][NTT];
#pragma unroll
    for (int mt = 0; mt < 4; ++mt)
#pragma unroll
        for (int nt = 0; nt < NTT; ++nt)
#pragma unroll
            for (int j = 0; j < 16; ++j) acc[mt][nt][j] = 0.0f;

    zero_oob<4, 256>(slab, slab + SLAB, tid, x0, y0);
    stage_async<CIN, 4, 256>(in_i, slab, tid, x0, y0, 0);

    int cur = 0;
    for (int kc = 0; kc < NCH; ++kc) {
        __syncthreads();
        if (kc + 1 < NCH)
            stage_async<CIN, 4, 256>(in_i, slab + (size_t)(cur ^ 1) * SLAB,
                                     tid, x0, y0, (kc + 1) * 32);

        const bf16* sb = slab + (size_t)cur * SLAB;
#pragma unroll
        for (int dxi = 0; dxi < 3; ++dxi) {
            const int dx = dxi - 1;
#pragma unroll
            for (int ks = 0; ks < 2; ++ks) {
                short8 af[4][2];             // [srow offset][x-half]
#pragma unroll
                for (int s = 0; s < 4; ++s)
#pragma unroll
                    for (int mx = 0; mx < 2; ++mx) {
                        const int px   = mx * 32 + ln31 + dx + 1;
                        const int slot = (ks * 2 + oct) ^ ((px >> 1) & 3);
                        af[s][mx] = *(const short8*)(sb + ((2 * rg + s) * 66 + px) * 32 + slot * 8);
                    }
#pragma unroll
                for (int dyi = 0; dyi < 3; ++dyi) {
                    const int t = dyi * 3 + dxi;
#pragma unroll
                    for (int nt = 0; nt < NTT; ++nt) {
                        const int gnt = ng * NTT + nt;
                        short8 bfr = *(const short8*)(wrb
                            + ((size_t)((((kc * 9 + t) * 2 + ks) * NTOT + gnt) * 64 + lane)) * 8);
#pragma unroll
                        for (int mt = 0; mt < 4; ++mt)
                            acc[mt][nt] = __builtin_amdgcn_mfma_f32_32x32x16_bf16(
                                              af[(mt >> 1) + dyi][mt & 1], bfr, acc[mt][nt], 0, 0, 0);
                    }
                }
            }
        }
        cur ^= 1;
    }

#pragma unroll
    for (int nt = 0; nt < NTT; ++nt) {
        const int co = (ng * NTT + nt) * 32 + ln31;
        const float bb = bias[co];
#pragma unroll
        for (int mt = 0; mt < 4; ++mt) {
            const int r  = 2 * rg + (mt >> 1);
            const int xb = x0 + (mt & 1) * 32;
#pragma unroll
            for (int j = 0; j < 16; ++j) {
                const int m = (j & 3) + 8 * (j >> 2) + 4 * oct;
                const float v = fmaxf(acc[mt][nt][j] + bb, 0.0f);
                out_i[((size_t)(y0 + r) * WW + (xb + m)) * COUT + co] = __float2bfloat16(v);
            }
        }
    }
}

// ---------------------------------------------------------------------------
// Merged heads: dbuf DMA staging, both kh and kv; lane-major coalesced B;
// per-pixel softmax over 11 channels via wave-private padded LDS transpose.
// ---------------------------------------------------------------------------
__global__ __launch_bounds__(256, 2) void head_mfma2(const bf16* __restrict__ in,
                                                     const bf16* __restrict__ wrp,
                                                     const float* __restrict__ bh,
                                                     const float* __restrict__ bv,
                                                     float* __restrict__ kh_base,
                                                     float* __restrict__ kv_base,
                                                     int b0)
{
    constexpr int SLABH = 6 * 66 * 32;
    __shared__ bf16  slab[2 * SLABH];       // 50,688 B
    __shared__ float smx[4][64][17];        // 17,408 B (wave-private slices)

    const int tid  = threadIdx.x;
    const int lane = tid & 63;
    const int wv   = tid >> 6;
    const int m    = lane & 15;
    const int q    = lane >> 4;
    const int img  = blockIdx.y >> 6;
    const int x0   = blockIdx.x * 64;
    const int y0   = (blockIdx.y & 63) * 4;
    const int y    = y0 + wv;

    const bf16* in_i = in + (size_t)img * HW * 64;

    f32x4 acc[4][2];
#pragma unroll
    for (int f = 0; f < 4; ++f) { acc[f][0] = (f32x4){0.f,0.f,0.f,0.f}; acc[f][1] = (f32x4){0.f,0.f,0.f,0.f}; }

    zero_oob<4, 256>(slab, slab + SLABH, tid, x0, y0);
    stage_async<64, 4, 256>(in_i, slab, tid, x0, y0, 0);

    int cur = 0;
    for (int kc = 0; kc < 2; ++kc) {
        __syncthreads();
        if (kc == 0)
            stage_async<64, 4, 256>(in_i, slab + SLABH, tid, x0, y0, 32);

        const bf16* sb = slab + (size_t)cur * SLABH;
#pragma unroll
        for (int t = 0; t < 9; ++t) {
            const int dy = t / 3 - 1, dx = t % 3 - 1;
            const int srow = wv + dy + 1;
            // lane-major: [kc][t][fr][lane][8] — one contiguous 512B frag per load
            short8 b0f = *(const short8*)(wrp + ((size_t)(((kc * 9 + t) * 2 + 0) * 64 + lane)) * 8);
            short8 b1f = *(const short8*)(wrp + ((size_t)(((kc * 9 + t) * 2 + 1) * 64 + lane)) * 8);
#pragma unroll
            for (int f = 0; f < 4; ++f) {
                const int px = f * 16 + m + dx + 1;
                const int slot = q ^ ((px >> 1) & 3);
                short8 a = *(const short8*)(sb + (srow * 66 + px) * 32 + slot * 8);
                acc[f][0] = __builtin_amdgcn_mfma_f32_16x16x32_bf16(a, b0f, acc[f][0], 0, 0, 0);
                acc[f][1] = __builtin_amdgcn_mfma_f32_16x16x32_bf16(a, b1f, acc[f][1], 0, 0, 0);
            }
        }
        cur ^= 1;
    }

    // two heads sequentially; smx slice is wave-private (no barrier needed)
#pragma unroll
    for (int head = 0; head < 2; ++head) {
        const float* bias = head ? bv : bh;
        const float bb = (m < 11) ? bias[m] : 0.0f;
#pragma unroll
        for (int f = 0; f < 4; ++f)
#pragma unroll
            for (int r = 0; r < 4; ++r)
                smx[wv][f * 16 + q * 4 + r][m] = acc[f][head][r] + bb;

        float v[11];
#pragma unroll
        for (int j = 0; j < 11; ++j) v[j] = smx[wv][lane][j];
        float mx = v[0];
#pragma unroll
        for (int j = 1; j < 11; ++j) mx = fmaxf(mx, v[j]);
        float s = 0.0f;
#pragma unroll
        for (int j = 0; j < 11; ++j) { v[j] = expf(v[j] - mx); s += v[j]; }
        const float inv = 1.0f / s;

        float* op = (head ? kv_base : kh_base) + (size_t)(b0 + img) * 11 * HW
                    + (size_t)y * WW + x0 + lane;
#pragma unroll
        for (int j = 0; j < 11; ++j)
            op[(size_t)j * HW] = v[j] * inv;
    }
}

// ---------------------------------------------------------------------------
// Horizontal separable pass (full batch): h = sum_i kh_i * shift_x(rgb, i-5)
// ---------------------------------------------------------------------------
__global__ __launch_bounds__(256) void hpass(const float* __restrict__ rgb,
                                             const float* __restrict__ kh,
                                             float* __restrict__ h)
{
    int idx = blockIdx.x * 256 + threadIdx.x;     // b*HW + p, total 524288
    int b = idx >> 16;                            // HW = 2^16
    int p = idx & (HW - 1);
    int y = p >> 8;
    int x = p & 255;

    float kw[11];
#pragma unroll
    for (int i = 0; i < 11; ++i) kw[i] = kh[((size_t)(b * 11 + i)) * HW + p];

#pragma unroll
    for (int c = 0; c < 3; ++c) {
        const float* rp = rgb + ((size_t)(b * 3 + c)) * HW + (size_t)y * WW;
        float s = 0.0f;
#pragma unroll
        for (int i = 0; i < 11; ++i) {
            int xx = x + i - 5;
            if (xx >= 0 && xx < WW) s = fmaf(kw[i], rp[xx], s);
        }
        h[((size_t)(b * 3 + c)) * HW + p] = s;
    }
}

// ---------------------------------------------------------------------------
// Vertical pass + depth-mask composite. Writes final, blurred, mask.
// ---------------------------------------------------------------------------
__global__ __launch_bounds__(256) void vpass_compose(const float* __restrict__ h,
                                                     const float* __restrict__ kv,
                                                     const float* __restrict__ rgb,
                                                     const float* __restrict__ depth,
                                                     float* __restrict__ fin,
                                                     float* __restrict__ blur,
                                                     float* __restrict__ masko)
{
    int idx = blockIdx.x * 256 + threadIdx.x;
    int b = idx >> 16;                            // HW = 2^16
    int p = idx & (HW - 1);
    int y = p >> 8;
    int x = p & 255;

    float kw[11];
#pragma unroll
    for (int i = 0; i < 11; ++i) kw[i] = kv[((size_t)(b * 11 + i)) * HW + p];

    float d = depth[idx];
    float mk = (d > 0.2f) ? 1.0f : 0.0f;
    masko[idx] = mk;

#pragma unroll
    for (int c = 0; c < 3; ++c) {
        const float* hp = h + ((size_t)(b * 3 + c)) * HW + x;
        float s = 0.0f;
#pragma unroll
        for (int i = 0; i < 11; ++i) {
            int yy = y + i - 5;
            if (yy >= 0 && yy < HH) s = fmaf(kw[i], hp[(size_t)yy * WW], s);
        }
        size_t o = ((size_t)(b * 3 + c)) * HW + p;
        blur[o] = s;
        fin[o] = mk * rgb[o] + (1.0f - mk) * s;
    }
}

// ---------------------------------------------------------------------------
extern "C" void kernel_launch(void* const* d_in, const int* in_sizes, int n_in,
                              void* d_out, int out_size, void* d_ws, size_t ws_size,
                              hipStream_t stream)
{
    const float* rgb   = (const float*)d_in[0];
    const float* depth = (const float*)d_in[1];
    const float* w1 = (const float*)d_in[2];  const float* b1 = (const float*)d_in[3];
    const float* w2 = (const float*)d_in[4];  const float* b2 = (const float*)d_in[5];
    const float* w3 = (const float*)d_in[6];  const float* b3 = (const float*)d_in[7];
    const float* w4 = (const float*)d_in[8];  const float* b4 = (const float*)d_in[9];
    const float* w5 = (const float*)d_in[10]; const float* b5 = (const float*)d_in[11];
    const float* wh = (const float*)d_in[12]; const float* bh = (const float*)d_in[13];
    const float* wv = (const float*)d_in[14]; const float* bv = (const float*)d_in[15];

    float* out    = (float*)d_out;
    float* fin_o  = out;                    // [8,3,256,256]
    float* blur_o = out + 1572864;          // [8,3,256,256]
    float* kh_o   = out + 3145728;          // [8,11,256,256]
    float* kv_o   = out + 8912896;          // [8,11,256,256]
    float* mask_o = out + 14680064;         // [8,1,256,256]

    // --- Select batch group size G from ws_size (deterministic -> graph-safe).
    const size_t perG = (size_t)HW * 2 * (128 + 64 + 128);   // 41.9 MB per image
    const size_t wsz  = (size_t)1 * 1024 * 1024;
    int G = 1;
    if (ws_size >= 8 * perG + wsz) G = 8;
    else if (ws_size >= 4 * perG + wsz) G = 4;
    else if (ws_size >= 2 * perG + wsz) G = 2;

    char* ws = (char*)d_ws;
    const size_t szA = (size_t)G * HW * 128 * 2;
    const size_t szB = (size_t)G * HW * 64 * 2;
    const size_t szC = (size_t)G * HW * 128 * 2;
    bf16* bufA = (bf16*)ws;
    bf16* bufB = (bf16*)(ws + szA);
    bf16* bufC = (bf16*)(ws + szA + szB);
    float* hbuf = (float*)bufC;              // 6.3 MB <= szC

    bf16* w2r  = (bf16*)(ws + szA + szB + szC);
    bf16* w3r  = w2r + 9 * 64 * 64;
    bf16* w4r  = w3r + 9 * 128 * 64;
    bf16* w5r  = w4r + 9 * 128 * 128;
    bf16* whvr = w5r + 9 * 64 * 128;         // [2][9][2][64][8] lane-major

    dim3 blk(256);

    // one-time weight reorders (graph-safe: identical work every call)
    reorder_w_cl<64, 64>  <<<dim3((9*64*64   + 255) / 256), blk, 0, stream>>>(w2, w2r);
    reorder_w_cl<128, 64> <<<dim3((9*128*64  + 255) / 256), blk, 0, stream>>>(w3, w3r);
    reorder_w_cl<128, 128><<<dim3((9*128*128 + 255) / 256), blk, 0, stream>>>(w4, w4r);
    reorder_w_cl<64, 128> <<<dim3((9*64*128  + 255) / 256), blk, 0, stream>>>(w5, w5r);
    reorder_w_head2_lm    <<<dim3((18432     + 255) / 256), blk, 0, stream>>>(wh, wv, whvr);

    for (int b0 = 0; b0 < BB; b0 += G) {
        conv3x3_first<16><<<dim3(4, 64 * G, 4), blk, 0, stream>>>(rgb, depth, w1, b1, bufA, b0);
        // COUT=64 layers: v13 (dy-reuse A-cache); COUT=128: v12 (reg-bound).
        conv_mfma_v13<64, 64, 3>  <<<dim3(4, 64 * G), blk, 0, stream>>>(bufA, w2r, b2, bufB);
        conv_mfma_v12<64, 128, 2> <<<dim3(4, 64 * G), blk, 0, stream>>>(bufB, w3r, b3, bufC);
        conv_mfma_v12<128, 128, 2><<<dim3(4, 64 * G), blk, 0, stream>>>(bufC, w4r, b4, bufA);
        conv_mfma_v13<128, 64, 3> <<<dim3(4, 64 * G), blk, 0, stream>>>(bufA, w5r, b5, bufB);
        head_mfma2<<<dim3(4, 64 * G), blk, 0, stream>>>(bufB, whvr, bh, bv, kh_o, kv_o, b0);
    }

    // separable blur + composite (full batch; bufC conv use dead by now)
    hpass<<<dim3(2048), blk, 0, stream>>>(rgb, kh_o, hbuf);
    vpass_compose<<<dim3(2048), blk, 0, stream>>>(hbuf, kv_o, rgb, depth,
                                                  fin_o, blur_o, mask_o);
}